// Round 1
// baseline (481.424 us; speedup 1.0000x reference)
//
#include <hip/hip_runtime.h>

#define D 128

// ---------------------------------------------------------------- utilities
__global__ void zero_u32(unsigned* p, int n) {
  int i = blockIdx.x * blockDim.x + threadIdx.x;
  int stride = gridDim.x * blockDim.x;
  for (; i < n; i += stride) p[i] = 0u;
}

__global__ void count_deg(const int* __restrict__ src, const int* __restrict__ dst,
                          unsigned* cnt_out, unsigned* cnt_in, int E) {
  int e = blockIdx.x * blockDim.x + threadIdx.x;
  if (e < E) {
    atomicAdd(&cnt_out[src[e]], 1u);
    atomicAdd(&cnt_in[dst[e]], 1u);
  }
}

__global__ void make_rsqrt(const unsigned* __restrict__ cnt_out,
                           const unsigned* __restrict__ cnt_in,
                           float* __restrict__ rs_out, float* __restrict__ rs_in, int N) {
  int i = blockIdx.x * blockDim.x + threadIdx.x;
  if (i < N) {
    float vo = (float)cnt_out[i]; if (vo < 1.f) vo = 1.f;
    float vi = (float)cnt_in[i];  if (vi < 1.f) vi = 1.f;
    rs_out[i] = rsqrtf(vo);
    rs_in[i]  = rsqrtf(vi);
  }
}

// ------------------------------------------------------- 3-phase prefix scan
__global__ void scan_p1(const unsigned* __restrict__ cnt, int n,
                        int* __restrict__ excl, int* __restrict__ bsum) {
  __shared__ int s[256];
  int t = threadIdx.x;
  int i = blockIdx.x * 256 + t;
  int v = (i < n) ? (int)cnt[i] : 0;
  s[t] = v;
  __syncthreads();
  for (int off = 1; off < 256; off <<= 1) {
    int add = (t >= off) ? s[t - off] : 0;
    __syncthreads();
    s[t] += add;
    __syncthreads();
  }
  if (i < n) excl[i] = s[t] - v;          // intra-block exclusive
  if (t == 255) bsum[blockIdx.x] = s[255]; // block total
}

__global__ void scan_p2(int* bsum, int nb) {
  __shared__ int s[256];
  int t = threadIdx.x;
  int v = (t < nb) ? bsum[t] : 0;
  s[t] = v;
  __syncthreads();
  for (int off = 1; off < 256; off <<= 1) {
    int add = (t >= off) ? s[t - off] : 0;
    __syncthreads();
    s[t] += add;
    __syncthreads();
  }
  if (t < nb) bsum[t] = s[t] - v;          // exclusive block offsets
}

__global__ void scan_p3(int* __restrict__ row_ptr, int* __restrict__ cursor,
                        const int* __restrict__ bsum, int n, int E) {
  int i = blockIdx.x * blockDim.x + threadIdx.x;
  if (i < n) {
    int e = row_ptr[i] + bsum[i >> 8];
    row_ptr[i] = e;
    cursor[i]  = e;
  }
  if (i == 0) row_ptr[n] = E;
}

__global__ void fill_csr(const int* __restrict__ src, const int* __restrict__ dst,
                         int* cursor, int* __restrict__ csr_src, int E) {
  int e = blockIdx.x * blockDim.x + threadIdx.x;
  if (e < E) {
    int d = dst[e];
    int pos = atomicAdd(&cursor[d], 1);
    csr_src[pos] = src[e];
  }
}

// ------------------------------------------------------------------- SpMM
// One block (128 threads) per destination node. Thread t owns feature t.
__global__ void spmm(const float* __restrict__ X, const int* __restrict__ row_ptr,
                     const int* __restrict__ csr_src, const float* __restrict__ rs_src,
                     const float* __restrict__ rs_in, float* __restrict__ out, int N) {
  int n = blockIdx.x;
  int t = threadIdx.x;
  int beg = row_ptr[n], end = row_ptr[n + 1];
  float acc = 0.f;
  if (rs_src) {
    for (int e = beg; e < end; ++e) {
      int s = csr_src[e];
      acc += X[s * D + t] * rs_src[s];
    }
  } else {
    for (int e = beg; e < end; ++e) {
      int s = csr_src[e];
      acc += X[s * D + t];
    }
  }
  out[n * D + t] = acc * rs_in[n];
}

// ------------------------------------------------------------------- GEMM
// C[nrows x 128] = relu(M @ W + b) * postscale (optional, per row).
// Block: 256 threads = 16x16; thread computes 4 rows x 8 cols. W in LDS.
// Safe in-place (out == M): block touches only its own 64 rows; sync before store.
__global__ __launch_bounds__(256) void gemm_bias_relu(
    const float* __restrict__ M, const float* __restrict__ W,
    const float* __restrict__ bias, const float* __restrict__ postscale,
    float* __restrict__ out, int nrows) {
  __shared__ float Wl[D * D];  // 64 KB
  int t = threadIdx.x;
  {
    const float4* W4 = (const float4*)W;
    float4* Wl4 = (float4*)Wl;
#pragma unroll
    for (int i = 0; i < 16; ++i) Wl4[t + i * 256] = W4[t + i * 256];
  }
  __syncthreads();

  int tx = t & 15;   // col group: 8 cols
  int ty = t >> 4;   // row group: 4 rows
  int rbase = blockIdx.x * 64 + ty * 4;
  int c0 = tx * 8;

  float acc[4][8];
#pragma unroll
  for (int i = 0; i < 4; ++i)
#pragma unroll
    for (int c = 0; c < 8; ++c) acc[i][c] = 0.f;

  int r[4];
#pragma unroll
  for (int i = 0; i < 4; ++i) {
    r[i] = rbase + i;
    if (r[i] > nrows - 1) r[i] = nrows - 1;  // clamp; discarded at store
  }

  const float4* M4 = (const float4*)M;
  for (int k4 = 0; k4 < D / 4; ++k4) {
    float4 mv[4];
#pragma unroll
    for (int i = 0; i < 4; ++i) mv[i] = M4[r[i] * (D / 4) + k4];
    float mk[4][4];
#pragma unroll
    for (int i = 0; i < 4; ++i) {
      mk[i][0] = mv[i].x; mk[i][1] = mv[i].y; mk[i][2] = mv[i].z; mk[i][3] = mv[i].w;
    }
#pragma unroll
    for (int kk = 0; kk < 4; ++kk) {
      const float* wrow = Wl + (k4 * 4 + kk) * D + c0;
      float4 w0 = *(const float4*)(wrow);
      float4 w1 = *(const float4*)(wrow + 4);
      float wv[8] = {w0.x, w0.y, w0.z, w0.w, w1.x, w1.y, w1.z, w1.w};
#pragma unroll
      for (int i = 0; i < 4; ++i)
#pragma unroll
        for (int c = 0; c < 8; ++c) acc[i][c] += mk[i][kk] * wv[c];
    }
  }

  __syncthreads();  // all in-place reads of M complete before writes

#pragma unroll
  for (int i = 0; i < 4; ++i) {
    int rr = rbase + i;
    if (rr < nrows) {
      float ps = postscale ? postscale[rr] : 1.f;
      float4 o0, o1;
      o0.x = fmaxf(acc[i][0] + bias[c0 + 0], 0.f) * ps;
      o0.y = fmaxf(acc[i][1] + bias[c0 + 1], 0.f) * ps;
      o0.z = fmaxf(acc[i][2] + bias[c0 + 2], 0.f) * ps;
      o0.w = fmaxf(acc[i][3] + bias[c0 + 3], 0.f) * ps;
      o1.x = fmaxf(acc[i][4] + bias[c0 + 4], 0.f) * ps;
      o1.y = fmaxf(acc[i][5] + bias[c0 + 5], 0.f) * ps;
      o1.z = fmaxf(acc[i][6] + bias[c0 + 6], 0.f) * ps;
      o1.w = fmaxf(acc[i][7] + bias[c0 + 7], 0.f) * ps;
      *(float4*)(out + rr * D + c0)     = o0;
      *(float4*)(out + rr * D + c0 + 4) = o1;
    }
  }
}

// ------------------------------------------------------------------- score
// One wave (64 lanes) per score edge; lane handles features {lane, lane+64}.
__global__ void score_kernel(const float* __restrict__ H, const int* __restrict__ ss,
                             const int* __restrict__ sd, float* __restrict__ out, int ES) {
  int wid = (int)((blockIdx.x * blockDim.x + threadIdx.x) >> 6);
  int lane = threadIdx.x & 63;
  if (wid >= ES) return;
  int a = ss[wid], b = sd[wid];
  const float* pa = H + (size_t)a * D;
  const float* pb = H + (size_t)b * D;
  float p = pa[lane] * pb[lane] + pa[lane + 64] * pb[lane + 64];
#pragma unroll
  for (int off = 32; off > 0; off >>= 1) p += __shfl_xor(p, off, 64);
  if (lane == 0) out[wid] = p;
}

// ------------------------------------------------------------------ launch
extern "C" void kernel_launch(void* const* d_in, const int* in_sizes, int n_in,
                              void* d_out, int out_size, void* d_ws, size_t ws_size,
                              hipStream_t stream) {
  const float* x   = (const float*)d_in[0];
  const int* esrc  = (const int*)d_in[1];
  const int* edst  = (const int*)d_in[2];
  const int* ssrc  = (const int*)d_in[3];
  const int* sdst  = (const int*)d_in[4];
  const float* W1  = (const float*)d_in[5];
  const float* b1  = (const float*)d_in[6];
  const float* W2  = (const float*)d_in[7];
  const float* b2  = (const float*)d_in[8];
  float* out = (float*)d_out;

  const int N  = in_sizes[0] / D;  // 50000
  const int E  = in_sizes[1];      // 800000
  const int ES = in_sizes[3];      // 200000

  char* w = (char*)d_ws;
  auto take = [&](size_t bytes) {
    char* p = w;
    w += (bytes + 255) & ~(size_t)255;
    return p;
  };
  unsigned* cnt     = (unsigned*)take((size_t)2 * N * 4);  // [out | in]
  unsigned* cnt_out = cnt;
  unsigned* cnt_in  = cnt + N;
  float* rs_out = (float*)take((size_t)N * 4);
  float* rs_in  = (float*)take((size_t)N * 4);
  int* row_ptr  = (int*)take((size_t)(N + 1) * 4);
  int* cursor   = (int*)take((size_t)N * 4);
  int* bsum     = (int*)take(256 * 4);
  int* csr_src  = (int*)take((size_t)E * 4);
  float* bufA   = (float*)take((size_t)N * D * 4);
  float* bufB   = (float*)take((size_t)N * D * 4);

  int nb = (N + 255) / 256;

  zero_u32<<<(2 * N + 255) / 256, 256, 0, stream>>>(cnt, 2 * N);
  count_deg<<<(E + 255) / 256, 256, 0, stream>>>(esrc, edst, cnt_out, cnt_in, E);
  make_rsqrt<<<(N + 255) / 256, 256, 0, stream>>>(cnt_out, cnt_in, rs_out, rs_in, N);
  scan_p1<<<nb, 256, 0, stream>>>(cnt_in, N, row_ptr, bsum);
  scan_p2<<<1, 256, 0, stream>>>(bsum, nb);
  scan_p3<<<nb, 256, 0, stream>>>(row_ptr, cursor, bsum, N, E);
  fill_csr<<<(E + 255) / 256, 256, 0, stream>>>(esrc, edst, cursor, csr_src, E);

  // Layer 1: SpMM(x, scale by rs_out at gather) -> bufA; GEMM in-place,
  // epilogue pre-scales by rs_out for layer-2 gather.
  spmm<<<N, 128, 0, stream>>>(x, row_ptr, csr_src, rs_out, rs_in, bufA, N);
  gemm_bias_relu<<<(N + 63) / 64, 256, 0, stream>>>(bufA, W1, b1, rs_out, bufA, N);

  // Layer 2: SpMM(h1_scaled) -> bufB; GEMM in-place, no post-scale.
  spmm<<<N, 128, 0, stream>>>(bufA, row_ptr, csr_src, nullptr, rs_in, bufB, N);
  gemm_bias_relu<<<(N + 63) / 64, 256, 0, stream>>>(bufB, W2, b2, nullptr, bufB, N);

  score_kernel<<<(ES + 3) / 4, 256, 0, stream>>>(bufB, ssrc, sdst, out, ES);
}

// Round 2
// 425.043 us; speedup vs baseline: 1.1326x; 1.1326x over previous
//
#include <hip/hip_runtime.h>

#define D 128

// ---------------------------------------------------------------- utilities
__global__ void zero_u32(unsigned* p, int n) {
  int i = blockIdx.x * blockDim.x + threadIdx.x;
  int stride = gridDim.x * blockDim.x;
  for (; i < n; i += stride) p[i] = 0u;
}

__global__ void count_deg(const int* __restrict__ src, const int* __restrict__ dst,
                          unsigned* cnt_out, unsigned* cnt_in, int E) {
  int e = blockIdx.x * blockDim.x + threadIdx.x;
  if (e < E) {
    atomicAdd(&cnt_out[src[e]], 1u);
    atomicAdd(&cnt_in[dst[e]], 1u);
  }
}

__global__ void make_rsqrt(const unsigned* __restrict__ cnt_out,
                           const unsigned* __restrict__ cnt_in,
                           float* __restrict__ rs_out, float* __restrict__ rs_in, int N) {
  int i = blockIdx.x * blockDim.x + threadIdx.x;
  if (i < N) {
    float vo = (float)cnt_out[i]; if (vo < 1.f) vo = 1.f;
    float vi = (float)cnt_in[i];  if (vi < 1.f) vi = 1.f;
    rs_out[i] = rsqrtf(vo);
    rs_in[i]  = rsqrtf(vi);
  }
}

// xp[n] = x[n] * rs_out[n]  (per-row scale), float4-vectorized
__global__ void prescale_rows(const float* __restrict__ x, const float* __restrict__ rs,
                              float* __restrict__ xp, int total4) {
  int i = blockIdx.x * blockDim.x + threadIdx.x;
  if (i < total4) {
    int n = i >> 5;                       // 32 float4 per row
    float r = rs[n];
    float4 v = ((const float4*)x)[i];
    v.x *= r; v.y *= r; v.z *= r; v.w *= r;
    ((float4*)xp)[i] = v;
  }
}

// ------------------------------------------------------- 3-phase prefix scan
__global__ void scan_p1(const unsigned* __restrict__ cnt, int n,
                        int* __restrict__ excl, int* __restrict__ bsum) {
  __shared__ int s[256];
  int t = threadIdx.x;
  int i = blockIdx.x * 256 + t;
  int v = (i < n) ? (int)cnt[i] : 0;
  s[t] = v;
  __syncthreads();
  for (int off = 1; off < 256; off <<= 1) {
    int add = (t >= off) ? s[t - off] : 0;
    __syncthreads();
    s[t] += add;
    __syncthreads();
  }
  if (i < n) excl[i] = s[t] - v;
  if (t == 255) bsum[blockIdx.x] = s[255];
}

__global__ void scan_p2(int* bsum, int nb) {
  __shared__ int s[256];
  int t = threadIdx.x;
  int v = (t < nb) ? bsum[t] : 0;
  s[t] = v;
  __syncthreads();
  for (int off = 1; off < 256; off <<= 1) {
    int add = (t >= off) ? s[t - off] : 0;
    __syncthreads();
    s[t] += add;
    __syncthreads();
  }
  if (t < nb) bsum[t] = s[t] - v;
}

__global__ void scan_p3(int* __restrict__ row_ptr, int* __restrict__ cursor,
                        const int* __restrict__ bsum, int n, int E) {
  int i = blockIdx.x * blockDim.x + threadIdx.x;
  if (i < n) {
    int e = row_ptr[i] + bsum[i >> 8];
    row_ptr[i] = e;
    cursor[i]  = e;
  }
  if (i == 0) row_ptr[n] = E;
}

__global__ void fill_csr(const int* __restrict__ src, const int* __restrict__ dst,
                         int* cursor, int* __restrict__ csr_src, int E) {
  int e = blockIdx.x * blockDim.x + threadIdx.x;
  if (e < E) {
    int d = dst[e];
    int pos = atomicAdd(&cursor[d], 1);
    csr_src[pos] = src[e];
  }
}

// ------------------------------------------------------------------- SpMM
// One WAVE (64 lanes) per destination node; lane owns a float2 (full 512B row
// per wave instruction). Unroll-by-4 over edges: 4 independent row loads in
// flight. Input rows are pre-scaled by rsqrt(deg_out); output scaled by
// rsqrt(deg_in).
__global__ __launch_bounds__(256) void spmm(const float* __restrict__ X,
    const int* __restrict__ row_ptr, const int* __restrict__ csr_src,
    const float* __restrict__ rs_in, float* __restrict__ out, int N) {
  int n = blockIdx.x * 4 + (threadIdx.x >> 6);
  int lane = threadIdx.x & 63;
  if (n >= N) return;
  int beg = row_ptr[n], end = row_ptr[n + 1];
  float r = rs_in[n];
  const float2* X2 = (const float2*)X;
  float ax = 0.f, ay = 0.f;
  int e = beg;
  for (; e + 4 <= end; e += 4) {
    int s0 = csr_src[e];
    int s1 = csr_src[e + 1];
    int s2 = csr_src[e + 2];
    int s3 = csr_src[e + 3];
    float2 v0 = X2[(size_t)s0 * 64 + lane];
    float2 v1 = X2[(size_t)s1 * 64 + lane];
    float2 v2 = X2[(size_t)s2 * 64 + lane];
    float2 v3 = X2[(size_t)s3 * 64 + lane];
    ax += (v0.x + v1.x) + (v2.x + v3.x);
    ay += (v0.y + v1.y) + (v2.y + v3.y);
  }
  for (; e < end; ++e) {
    int s = csr_src[e];
    float2 v = X2[(size_t)s * 64 + lane];
    ax += v.x;
    ay += v.y;
  }
  float2 o;
  o.x = ax * r;
  o.y = ay * r;
  ((float2*)out)[(size_t)n * 64 + lane] = o;
}

// ------------------------------------------------------------------- GEMM
// C[nrows x 128] = relu(M @ W + b) * postscale (optional, per row).
// Block: 256 threads = 16x16; thread computes 4 rows x 8 cols. W in LDS.
// Safe in-place (out == M): block touches only its own 64 rows; sync before store.
__global__ __launch_bounds__(256) void gemm_bias_relu(
    const float* __restrict__ M, const float* __restrict__ W,
    const float* __restrict__ bias, const float* __restrict__ postscale,
    float* __restrict__ out, int nrows) {
  __shared__ float Wl[D * D];  // 64 KB
  int t = threadIdx.x;
  {
    const float4* W4 = (const float4*)W;
    float4* Wl4 = (float4*)Wl;
#pragma unroll
    for (int i = 0; i < 16; ++i) Wl4[t + i * 256] = W4[t + i * 256];
  }
  __syncthreads();

  int tx = t & 15;   // col group: 8 cols
  int ty = t >> 4;   // row group: 4 rows
  int rbase = blockIdx.x * 64 + ty * 4;
  int c0 = tx * 8;

  float acc[4][8];
#pragma unroll
  for (int i = 0; i < 4; ++i)
#pragma unroll
    for (int c = 0; c < 8; ++c) acc[i][c] = 0.f;

  int r[4];
#pragma unroll
  for (int i = 0; i < 4; ++i) {
    r[i] = rbase + i;
    if (r[i] > nrows - 1) r[i] = nrows - 1;  // clamp; discarded at store
  }

  const float4* M4 = (const float4*)M;
  for (int k4 = 0; k4 < D / 4; ++k4) {
    float4 mv[4];
#pragma unroll
    for (int i = 0; i < 4; ++i) mv[i] = M4[r[i] * (D / 4) + k4];
    float mk[4][4];
#pragma unroll
    for (int i = 0; i < 4; ++i) {
      mk[i][0] = mv[i].x; mk[i][1] = mv[i].y; mk[i][2] = mv[i].z; mk[i][3] = mv[i].w;
    }
#pragma unroll
    for (int kk = 0; kk < 4; ++kk) {
      const float* wrow = Wl + (k4 * 4 + kk) * D + c0;
      float4 w0 = *(const float4*)(wrow);
      float4 w1 = *(const float4*)(wrow + 4);
      float wv[8] = {w0.x, w0.y, w0.z, w0.w, w1.x, w1.y, w1.z, w1.w};
#pragma unroll
      for (int i = 0; i < 4; ++i)
#pragma unroll
        for (int c = 0; c < 8; ++c) acc[i][c] += mk[i][kk] * wv[c];
    }
  }

  __syncthreads();  // all in-place reads of M complete before writes

#pragma unroll
  for (int i = 0; i < 4; ++i) {
    int rr = rbase + i;
    if (rr < nrows) {
      float ps = postscale ? postscale[rr] : 1.f;
      float4 o0, o1;
      o0.x = fmaxf(acc[i][0] + bias[c0 + 0], 0.f) * ps;
      o0.y = fmaxf(acc[i][1] + bias[c0 + 1], 0.f) * ps;
      o0.z = fmaxf(acc[i][2] + bias[c0 + 2], 0.f) * ps;
      o0.w = fmaxf(acc[i][3] + bias[c0 + 3], 0.f) * ps;
      o1.x = fmaxf(acc[i][4] + bias[c0 + 4], 0.f) * ps;
      o1.y = fmaxf(acc[i][5] + bias[c0 + 5], 0.f) * ps;
      o1.z = fmaxf(acc[i][6] + bias[c0 + 6], 0.f) * ps;
      o1.w = fmaxf(acc[i][7] + bias[c0 + 7], 0.f) * ps;
      *(float4*)(out + rr * D + c0)     = o0;
      *(float4*)(out + rr * D + c0 + 4) = o1;
    }
  }
}

// ------------------------------------------------------------------- score
// One wave (64 lanes) per score edge; lane handles features {lane, lane+64}.
__global__ void score_kernel(const float* __restrict__ H, const int* __restrict__ ss,
                             const int* __restrict__ sd, float* __restrict__ out, int ES) {
  int wid = (int)((blockIdx.x * blockDim.x + threadIdx.x) >> 6);
  int lane = threadIdx.x & 63;
  if (wid >= ES) return;
  int a = ss[wid], b = sd[wid];
  const float* pa = H + (size_t)a * D;
  const float* pb = H + (size_t)b * D;
  float p = pa[lane] * pb[lane] + pa[lane + 64] * pb[lane + 64];
#pragma unroll
  for (int off = 32; off > 0; off >>= 1) p += __shfl_xor(p, off, 64);
  if (lane == 0) out[wid] = p;
}

// ------------------------------------------------------------------ launch
extern "C" void kernel_launch(void* const* d_in, const int* in_sizes, int n_in,
                              void* d_out, int out_size, void* d_ws, size_t ws_size,
                              hipStream_t stream) {
  const float* x   = (const float*)d_in[0];
  const int* esrc  = (const int*)d_in[1];
  const int* edst  = (const int*)d_in[2];
  const int* ssrc  = (const int*)d_in[3];
  const int* sdst  = (const int*)d_in[4];
  const float* W1  = (const float*)d_in[5];
  const float* b1  = (const float*)d_in[6];
  const float* W2  = (const float*)d_in[7];
  const float* b2  = (const float*)d_in[8];
  float* out = (float*)d_out;

  const int N  = in_sizes[0] / D;  // 50000
  const int E  = in_sizes[1];      // 800000
  const int ES = in_sizes[3];      // 200000

  char* w = (char*)d_ws;
  auto take = [&](size_t bytes) {
    char* p = w;
    w += (bytes + 255) & ~(size_t)255;
    return p;
  };
  unsigned* cnt     = (unsigned*)take((size_t)2 * N * 4);  // [out | in]
  unsigned* cnt_out = cnt;
  unsigned* cnt_in  = cnt + N;
  float* rs_out = (float*)take((size_t)N * 4);
  float* rs_in  = (float*)take((size_t)N * 4);
  int* row_ptr  = (int*)take((size_t)(N + 1) * 4);
  int* cursor   = (int*)take((size_t)N * 4);
  int* bsum     = (int*)take(256 * 4);
  int* csr_src  = (int*)take((size_t)E * 4);
  float* bufA   = (float*)take((size_t)N * D * 4);
  float* bufB   = (float*)take((size_t)N * D * 4);

  int nb = (N + 255) / 256;

  zero_u32<<<(2 * N + 255) / 256, 256, 0, stream>>>(cnt, 2 * N);
  count_deg<<<(E + 255) / 256, 256, 0, stream>>>(esrc, edst, cnt_out, cnt_in, E);
  make_rsqrt<<<(N + 255) / 256, 256, 0, stream>>>(cnt_out, cnt_in, rs_out, rs_in, N);
  scan_p1<<<nb, 256, 0, stream>>>(cnt_in, N, row_ptr, bsum);
  scan_p2<<<1, 256, 0, stream>>>(bsum, nb);
  scan_p3<<<nb, 256, 0, stream>>>(row_ptr, cursor, bsum, N, E);
  fill_csr<<<(E + 255) / 256, 256, 0, stream>>>(esrc, edst, cursor, csr_src, E);

  // Prescale x by rsqrt(deg_out) into bufB (free until layer-2 SpMM writes it).
  prescale_rows<<<(N * 32 + 255) / 256, 256, 0, stream>>>(x, rs_out, bufB, N * 32);

  // Layer 1: SpMM(x_prescaled) -> bufA; GEMM in-place, epilogue pre-scales
  // by rs_out so h1 is ready for layer-2 gather.
  spmm<<<(N + 3) / 4, 256, 0, stream>>>(bufB, row_ptr, csr_src, rs_in, bufA, N);
  gemm_bias_relu<<<(N + 63) / 64, 256, 0, stream>>>(bufA, W1, b1, rs_out, bufA, N);

  // Layer 2: SpMM(h1_prescaled) -> bufB; GEMM in-place, no post-scale.
  spmm<<<(N + 3) / 4, 256, 0, stream>>>(bufA, row_ptr, csr_src, rs_in, bufB, N);
  gemm_bias_relu<<<(N + 63) / 64, 256, 0, stream>>>(bufB, W2, b2, nullptr, bufB, N);

  score_kernel<<<(ES + 3) / 4, 256, 0, stream>>>(bufB, ssrc, sdst, out, ES);
}